// Round 1
// baseline (20048.796 us; speedup 1.0000x reference)
//
#include <hip/hip_runtime.h>
#include <stdint.h>

#define SEQ    512
#define NBATCH 64
#define HID    1024
#define GDIM   4096

typedef __attribute__((ext_vector_type(4))) float          f32x4;
typedef __attribute__((ext_vector_type(8))) short          s16x8;
typedef __attribute__((ext_vector_type(4))) unsigned short u16x4;

#define MFMA_BF16(a,b,c) __builtin_amdgcn_mfma_f32_16x16x32_bf16((a),(b),(c),0,0,0)

__device__ __forceinline__ unsigned short f2bf(float f){
  union { float f; unsigned u; } v; v.f = f;
  unsigned r = v.u + 0x7fffu + ((v.u >> 16) & 1u);
  return (unsigned short)(r >> 16);
}

__device__ __forceinline__ void gload_lds16(const void* g, void* l){
  __builtin_amdgcn_global_load_lds((const __attribute__((address_space(1))) void*)g,
                                   (__attribute__((address_space(3))) void*)l,
                                   16, 0, 0);
}

// ---------------- fp32 -> bf16 bulk convert (n4 = elements/4) ----------------
__global__ __launch_bounds__(256) void cvt_bf16(const float* __restrict__ s,
                                                unsigned short* __restrict__ d, int n4){
  int i = blockIdx.x*256 + threadIdx.x;
  if (i >= n4) return;
  f32x4 v = *(const f32x4*)(s + (size_t)i*4);
  u16x4 o;
  o[0]=f2bf(v[0]); o[1]=f2bf(v[1]); o[2]=f2bf(v[2]); o[3]=f2bf(v[3]);
  *(u16x4*)(d + (size_t)i*4) = o;
}

// ---------------- init: h0 -> hbuf[0] (bf16), c0 -> cstate ----------------
__global__ __launch_bounds__(256) void init_state(const float* __restrict__ h0,
                                                  const float* __restrict__ c0,
                                                  unsigned short* __restrict__ hbuf,
                                                  float* __restrict__ cstate){
  int i = blockIdx.x*256 + threadIdx.x;   // 65536 total
  hbuf[i]   = f2bf(h0[i]);
  cstate[i] = c0[i];
}

// ---------------- x_proj GEMM: C[M][4096] = A[M][1024] * Bw[4096][1024]^T + bias ----
// m97-style: 128x128 tile, BK=64, double-buffered LDS via global_load_lds(16B).
__global__ __launch_bounds__(256,1) void gemm_xproj(
    const unsigned short* __restrict__ A,   // bf16 [M][1024]
    const unsigned short* __restrict__ Bw,  // bf16 [4096][1024]
    const float* __restrict__ bih, const float* __restrict__ bhh,
    float* __restrict__ C, int M)
{
  __shared__ unsigned short Al[2][128*64];
  __shared__ unsigned short Bl[2][128*64];

  const int bm = blockIdx.x >> 5;          // M/128 tiles
  const int bn = blockIdx.x & 31;          // 4096/128 = 32
  const int tid = threadIdx.x;
  const int wv = tid >> 6, l = tid & 63;
  const int wm = wv >> 1, wn = wv & 1;
  const int c16 = l & 15, rq = l >> 4;

  const unsigned short* Ab = A  + (size_t)bm*128*1024;
  const unsigned short* Bb = Bw + (size_t)bn*128*1024;

  f32x4 acc[4][4];
#pragma unroll
  for (int i=0;i<4;++i)
#pragma unroll
    for (int j=0;j<4;++j) acc[i][j] = (f32x4){0.f,0.f,0.f,0.f};

  auto stage = [&](int buf, int kt){
    const int k0 = kt*64;
    const int rsub = wv*8 + (l>>3);
    const int col  = (l&7)*8;
#pragma unroll
    for (int is=0; is<4; ++is){
      const int row = is*32 + rsub;
      gload_lds16(Ab + (size_t)row*1024 + k0 + col, &Al[buf][row*64 + col]);
      gload_lds16(Bb + (size_t)row*1024 + k0 + col, &Bl[buf][row*64 + col]);
    }
  };

  stage(0, 0);
  asm volatile("s_waitcnt vmcnt(0)" ::: "memory");
  __syncthreads();

  for (int kt = 0; kt < 16; ++kt){
    const int cur = kt & 1;
    if (kt < 15) stage(cur^1, kt+1);
#pragma unroll
    for (int ks=0; ks<2; ++ks){
      s16x8 afr[4], bfr[4];
#pragma unroll
      for (int mi=0;mi<4;++mi)
        afr[mi] = *(const s16x8*)&Al[cur][(wm*64 + mi*16 + c16)*64 + ks*32 + rq*8];
#pragma unroll
      for (int ni=0;ni<4;++ni)
        bfr[ni] = *(const s16x8*)&Bl[cur][(wn*64 + ni*16 + c16)*64 + ks*32 + rq*8];
#pragma unroll
      for (int mi=0;mi<4;++mi)
#pragma unroll
        for (int ni=0;ni<4;++ni)
          acc[mi][ni] = MFMA_BF16(afr[mi], bfr[ni], acc[mi][ni]);
    }
    asm volatile("s_waitcnt vmcnt(0)" ::: "memory");
    __syncthreads();
  }

  const int crow0 = bm*128 + wm*64;
  const int ccol0 = bn*128 + wn*64;
#pragma unroll
  for (int ni=0;ni<4;++ni){
    const int col = ccol0 + ni*16 + c16;
    const float bsum = bih[col] + bhh[col];
#pragma unroll
    for (int mi=0;mi<4;++mi){
      const int row = crow0 + mi*16 + rq*4;
#pragma unroll
      for (int r=0;r<4;++r)
        C[(size_t)(row+r)*GDIM + col] = acc[mi][ni][r] + bsum;
    }
  }
}

// ---------------- persistent recurrence over one chunk of timesteps ----------------
// 128 blocks x 512 threads. Block b owns hidden cols [8b, 8b+8) -> 32 gate rows.
// 8 waves = (batch-tile mt 0..3) x (K-half kh 0..1). W_hh slice in registers.
__global__ __launch_bounds__(512,2) void lstm_rec(
    const float* __restrict__ whh,     // fp32 [4096][1024]
    const float* __restrict__ xproj,   // fp32 [nsteps*64][4096]
    unsigned short* __restrict__ hbuf, // bf16 [3][64*1024] ring
    float* __restrict__ cstate,        // fp32 [64*1024]
    float* __restrict__ outp,          // fp32 d_out base
    unsigned int* __restrict__ bar,    // [512] counters (zeroed per call)
    int t0, int nsteps)
{
  const int tid = threadIdx.x;
  const int wv = tid >> 6, l = tid & 63;
  const int mt = wv >> 1, kh = wv & 1;
  const int c16 = l & 15, rq = l >> 4;
  const int hc0 = blockIdx.x * 8;
  // epilogue mapping: one (batch, hidden-col) pair per thread
  const int eb = tid >> 3, ej = tid & 7;

  __shared__ float part[8*16*33];      // [wave][b_local][n(padded 33)]

  // ---- load W_hh slice into registers (bf16 frags), n_local = j*4 + g
  s16x8 breg[32];
#pragma unroll
  for (int tn = 0; tn < 2; ++tn){
#pragma unroll
    for (int ks = 0; ks < 16; ++ks){
      const int nl = tn*16 + c16;
      const int j = nl >> 2, g = nl & 3;
      const int grow = g*HID + hc0 + j;
      const int k = kh*512 + ks*32 + rq*8;
      const float* wp = whh + (size_t)grow*HID + k;
      f32x4 a = *(const f32x4*)wp;
      f32x4 b = *(const f32x4*)(wp + 4);
      s16x8 fr;
      fr[0]=(short)f2bf(a[0]); fr[1]=(short)f2bf(a[1]);
      fr[2]=(short)f2bf(a[2]); fr[3]=(short)f2bf(a[3]);
      fr[4]=(short)f2bf(b[0]); fr[5]=(short)f2bf(b[1]);
      fr[6]=(short)f2bf(b[2]); fr[7]=(short)f2bf(b[3]);
      breg[tn*16+ks] = fr;
    }
  }

  float creg = cstate[(size_t)eb*HID + hc0 + ej];

  int rb = t0 % 3;
  for (int t = t0; t < t0 + nsteps; ++t){
    int wb = rb + 1; if (wb == 3) wb = 0;

    // x_proj for this thread's (b, j), issued early
    const size_t xrow = (size_t)(t - t0)*NBATCH + eb;
    const float xp0 = xproj[xrow*GDIM + 0*HID + hc0 + ej];
    const float xp1 = xproj[xrow*GDIM + 1*HID + hc0 + ej];
    const float xp2 = xproj[xrow*GDIM + 2*HID + hc0 + ej];
    const float xp3 = xproj[xrow*GDIM + 3*HID + hc0 + ej];

    // ---- MFMA: partial gates for this wave's (batch-tile, K-half)
    f32x4 acc0 = (f32x4){0.f,0.f,0.f,0.f};
    f32x4 acc1 = (f32x4){0.f,0.f,0.f,0.f};
    const unsigned short* hrow = hbuf + (size_t)rb*65536
                               + (size_t)(mt*16 + c16)*HID + kh*512 + rq*8;
#pragma unroll
    for (int ks = 0; ks < 16; ++ks){
      s16x8 af = *(const s16x8*)(hrow + ks*32);
      acc0 = MFMA_BF16(af, breg[ks],      acc0);
      acc1 = MFMA_BF16(af, breg[16 + ks], acc1);
    }

    // ---- write partials to LDS
#pragma unroll
    for (int r = 0; r < 4; ++r){
      const int bl = rq*4 + r;
      part[(wv*16 + bl)*33 + c16]      = acc0[r];
      part[(wv*16 + bl)*33 + 16 + c16] = acc1[r];
    }
    __syncthreads();

    // ---- epilogue: sum K-halves, activations, state update
    const int mt_e = eb >> 4, bl_e = eb & 15;
    const int b0 = ((mt_e*2 + 0)*16 + bl_e)*33;
    const int b1 = ((mt_e*2 + 1)*16 + bl_e)*33;
    const float vi = part[b0 + ej*4 + 0] + part[b1 + ej*4 + 0] + xp0;
    const float vf = part[b0 + ej*4 + 1] + part[b1 + ej*4 + 1] + xp1;
    const float vg = part[b0 + ej*4 + 2] + part[b1 + ej*4 + 2] + xp2;
    const float vo = part[b0 + ej*4 + 3] + part[b1 + ej*4 + 3] + xp3;

    const float ig = 1.f/(1.f + __expf(-vi));
    const float fg = 1.f/(1.f + __expf(-vf));
    const float gg = tanhf(vg);
    const float og = 1.f/(1.f + __expf(-vo));
    creg = fg*creg + ig*gg;
    const float h = og * tanhf(creg);

    const size_t oidx = (size_t)eb*HID + hc0 + ej;
    outp[(size_t)t*65536 + oidx] = h;
    hbuf[(size_t)wb*65536 + oidx] = f2bf(h);
    if (t == SEQ-1){
      outp[(size_t)SEQ*65536 + oidx]         = h;     // h_last
      outp[(size_t)SEQ*65536 + 65536 + oidx] = creg;  // c_last
    }

    // ---- grid barrier (release-add + acquire-spin, bounded failsafe)
    __threadfence();
    __syncthreads();
    if (tid == 0){
      __hip_atomic_fetch_add(&bar[t], 1u, __ATOMIC_RELEASE, __HIP_MEMORY_SCOPE_AGENT);
      int spins = 0;
      while (__hip_atomic_load(&bar[t], __ATOMIC_ACQUIRE, __HIP_MEMORY_SCOPE_AGENT)
             < (unsigned)gridDim.x){
        __builtin_amdgcn_s_sleep(1);
        if (++spins > (1<<22)) break;
      }
    }
    __syncthreads();

    rb = wb;
  }

  cstate[(size_t)eb*HID + hc0 + ej] = creg;
}

// ---------------------------------------------------------------------------
extern "C" void kernel_launch(void* const* d_in, const int* in_sizes, int n_in,
                              void* d_out, int out_size, void* d_ws, size_t ws_size,
                              hipStream_t stream)
{
  const float* inp = (const float*)d_in[0];
  const float* wih = (const float*)d_in[1];
  const float* whh = (const float*)d_in[2];
  const float* bih = (const float*)d_in[3];
  const float* bhh = (const float*)d_in[4];
  const float* h0  = (const float*)d_in[5];
  const float* c0  = (const float*)d_in[6];
  float* outp = (float*)d_out;

  auto alignup = [](size_t x){ return (x + 255) & ~(size_t)255; };
  auto need = [&](size_t ch)->size_t{
    size_t s = 0;
    s += alignup(ch*64*4096*4);          // xproj chunk
    s += alignup(ch*64*1024*2);          // in_bf16 chunk
    s += alignup((size_t)4096*1024*2);   // wih_bf16
    s += alignup((size_t)3*64*1024*2);   // hbuf ring
    s += alignup((size_t)64*1024*4);     // cstate
    s += alignup((size_t)512*4);         // barriers
    return s;
  };
  int CH = 64;
  while (CH > 2 && need(CH) > ws_size) CH >>= 1;

  char* w = (char*)d_ws;
  float*          xproj  = (float*)w;          w += alignup((size_t)CH*64*4096*4);
  unsigned short* in_bf  = (unsigned short*)w; w += alignup((size_t)CH*64*1024*2);
  unsigned short* wih_bf = (unsigned short*)w; w += alignup((size_t)4096*1024*2);
  unsigned short* hbuf   = (unsigned short*)w; w += alignup((size_t)3*64*1024*2);
  float*          cst    = (float*)w;          w += alignup((size_t)64*1024*4);
  unsigned int*   bar    = (unsigned int*)w;

  hipMemsetAsync(bar, 0, 512*sizeof(unsigned int), stream);

  // W_ih -> bf16 (once per call); init h/c state
  cvt_bf16<<<4096, 256, 0, stream>>>(wih, wih_bf, 4096*1024/4);
  init_state<<<256, 256, 0, stream>>>(h0, c0, hbuf, cst);

  const int nch = SEQ / CH;
  for (int ci = 0; ci < nch; ++ci){
    const int t0 = ci * CH;
    const int n4 = CH*64*1024/4;
    cvt_bf16<<<(n4+255)/256, 256, 0, stream>>>(inp + (size_t)t0*65536, in_bf, n4);
    gemm_xproj<<<dim3((CH*64/128)*32), 256, 0, stream>>>(in_bf, wih_bf, bih, bhh,
                                                         xproj, CH*64);
    lstm_rec<<<dim3(128), dim3(512), 0, stream>>>(whh, xproj, hbuf, cst, outp,
                                                  bar, t0, CH);
  }
}

// Round 2
// 4145.667 us; speedup vs baseline: 4.8361x; 4.8361x over previous
//
#include <hip/hip_runtime.h>
#include <stdint.h>

#define SEQ    512
#define NBATCH 64
#define HID    1024
#define GDIM   4096

typedef __attribute__((ext_vector_type(4))) float          f32x4;
typedef __attribute__((ext_vector_type(8))) short          s16x8;
typedef __attribute__((ext_vector_type(4))) unsigned short u16x4;

#define MFMA_BF16(a,b,c) __builtin_amdgcn_mfma_f32_16x16x32_bf16((a),(b),(c),0,0,0)

__device__ __forceinline__ unsigned short f2bf(float f){
  union { float f; unsigned u; } v; v.f = f;
  unsigned r = v.u + 0x7fffu + ((v.u >> 16) & 1u);
  return (unsigned short)(r >> 16);
}

__device__ __forceinline__ void gload_lds16(const void* g, void* l){
  __builtin_amdgcn_global_load_lds((const __attribute__((address_space(1))) void*)g,
                                   (__attribute__((address_space(3))) void*)l,
                                   16, 0, 0);
}

// ---------------- fp32 -> bf16 bulk convert (n4 = elements/4) ----------------
__global__ __launch_bounds__(256) void cvt_bf16(const float* __restrict__ s,
                                                unsigned short* __restrict__ d, int n4){
  int i = blockIdx.x*256 + threadIdx.x;
  if (i >= n4) return;
  f32x4 v = *(const f32x4*)(s + (size_t)i*4);
  u16x4 o;
  o[0]=f2bf(v[0]); o[1]=f2bf(v[1]); o[2]=f2bf(v[2]); o[3]=f2bf(v[3]);
  *(u16x4*)(d + (size_t)i*4) = o;
}

// ---------------- init: h0 -> hbuf[0] (bf16), c0 -> cstate ----------------
__global__ __launch_bounds__(256) void init_state(const float* __restrict__ h0,
                                                  const float* __restrict__ c0,
                                                  unsigned short* __restrict__ hbuf,
                                                  float* __restrict__ cstate){
  int i = blockIdx.x*256 + threadIdx.x;   // 65536 total
  hbuf[i]   = f2bf(h0[i]);
  cstate[i] = c0[i];
}

// ---------------- x_proj GEMM: C[M][4096] = A[M][1024] * Bw[4096][1024]^T + bias ----
__global__ __launch_bounds__(256,1) void gemm_xproj(
    const unsigned short* __restrict__ A,   // bf16 [M][1024]
    const unsigned short* __restrict__ Bw,  // bf16 [4096][1024]
    const float* __restrict__ bih, const float* __restrict__ bhh,
    float* __restrict__ C, int M)
{
  __shared__ unsigned short Al[2][128*64];
  __shared__ unsigned short Bl[2][128*64];

  const int bm = blockIdx.x >> 5;
  const int bn = blockIdx.x & 31;
  const int tid = threadIdx.x;
  const int wv = tid >> 6, l = tid & 63;
  const int wm = wv >> 1, wn = wv & 1;
  const int c16 = l & 15, rq = l >> 4;

  const unsigned short* Ab = A  + (size_t)bm*128*1024;
  const unsigned short* Bb = Bw + (size_t)bn*128*1024;

  f32x4 acc[4][4];
#pragma unroll
  for (int i=0;i<4;++i)
#pragma unroll
    for (int j=0;j<4;++j) acc[i][j] = (f32x4){0.f,0.f,0.f,0.f};

  auto stage = [&](int buf, int kt){
    const int k0 = kt*64;
    const int rsub = wv*8 + (l>>3);
    const int col  = (l&7)*8;
#pragma unroll
    for (int is=0; is<4; ++is){
      const int row = is*32 + rsub;
      gload_lds16(Ab + (size_t)row*1024 + k0 + col, &Al[buf][row*64 + col]);
      gload_lds16(Bb + (size_t)row*1024 + k0 + col, &Bl[buf][row*64 + col]);
    }
  };

  stage(0, 0);
  asm volatile("s_waitcnt vmcnt(0)" ::: "memory");
  __syncthreads();

  for (int kt = 0; kt < 16; ++kt){
    const int cur = kt & 1;
    if (kt < 15) stage(cur^1, kt+1);
#pragma unroll
    for (int ks=0; ks<2; ++ks){
      s16x8 afr[4], bfr[4];
#pragma unroll
      for (int mi=0;mi<4;++mi)
        afr[mi] = *(const s16x8*)&Al[cur][(wm*64 + mi*16 + c16)*64 + ks*32 + rq*8];
#pragma unroll
      for (int ni=0;ni<4;++ni)
        bfr[ni] = *(const s16x8*)&Bl[cur][(wn*64 + ni*16 + c16)*64 + ks*32 + rq*8];
#pragma unroll
      for (int mi=0;mi<4;++mi)
#pragma unroll
        for (int ni=0;ni<4;++ni)
          acc[mi][ni] = MFMA_BF16(afr[mi], bfr[ni], acc[mi][ni]);
    }
    asm volatile("s_waitcnt vmcnt(0)" ::: "memory");
    __syncthreads();
  }

  const int crow0 = bm*128 + wm*64;
  const int ccol0 = bn*128 + wn*64;
#pragma unroll
  for (int ni=0;ni<4;++ni){
    const int col = ccol0 + ni*16 + c16;
    const float bsum = bih[col] + bhh[col];
#pragma unroll
    for (int mi=0;mi<4;++mi){
      const int row = crow0 + mi*16 + rq*4;
#pragma unroll
      for (int r=0;r<4;++r)
        C[(size_t)(row+r)*GDIM + col] = acc[mi][ni][r] + bsum;
    }
  }
}

// ---------------- persistent recurrence over one chunk of timesteps ----------------
// 128 blocks x 512 threads. Block b owns hidden cols [8b, 8b+8) -> 32 gate rows.
// Sync protocol: h + flags live at the LLC via sc0/sc1 loads/stores; release is
// s_waitcnt vmcnt(0) only (no threadfence / wbl2 / inv). Flags are monotonic
// per-block step counters in separate 128B lines; 128 threads poll in parallel.
__global__ __launch_bounds__(512,2) void lstm_rec(
    const unsigned short* __restrict__ whhb,   // bf16 [4096][1024]
    const float* __restrict__ xproj,           // fp32 [nsteps*64][4096]
    unsigned short* __restrict__ hbuf,         // bf16 [3][64*1024] ring
    float* __restrict__ cstate,                // fp32 [64*1024]
    float* __restrict__ outp,                  // fp32 d_out base
    unsigned int* __restrict__ bar,            // 128 flags, stride 32 uints
    int t0, int nsteps)
{
  const int tid = threadIdx.x;
  const int wv = tid >> 6, l = tid & 63;
  const int mt = wv >> 1, kh = wv & 1;
  const int c16 = l & 15, rq = l >> 4;
  const int hc0 = blockIdx.x * 8;
  const int eb = tid >> 3, ej = tid & 7;      // epilogue (batch, hidden-col)

  __shared__ float part[8*16*33];             // [wave][b_local][n(padded 33)]

  // ---- W_hh slice -> registers (bf16 frags), n_local = j*4 + g
  s16x8 breg[32];
#pragma unroll
  for (int tn = 0; tn < 2; ++tn)
#pragma unroll
    for (int ks = 0; ks < 16; ++ks){
      const int nl = tn*16 + c16;
      const int j = nl >> 2, g = nl & 3;
      const int grow = g*HID + hc0 + j;
      const int k = kh*512 + ks*32 + rq*8;
      breg[tn*16+ks] = *(const s16x8*)(whhb + (size_t)grow*HID + k);
    }

  float creg = cstate[(size_t)eb*HID + hc0 + ej];

  int rb = t0 % 3;
  for (int t = t0; t < t0 + nsteps; ++t){
    int wb = rb + 1; if (wb == 3) wb = 0;

    const size_t xrow = (size_t)(t - t0)*NBATCH + eb;
    const float xp0 = xproj[xrow*GDIM + 0*HID + hc0 + ej];
    const float xp1 = xproj[xrow*GDIM + 1*HID + hc0 + ej];
    const float xp2 = xproj[xrow*GDIM + 2*HID + hc0 + ej];
    const float xp3 = xproj[xrow*GDIM + 3*HID + hc0 + ej];

    // ---- h fragments from LLC (bypass L1/L2: sc0 sc1)
    const unsigned short* hrow = hbuf + (size_t)rb*65536
                               + (size_t)(mt*16 + c16)*HID + kh*512 + rq*8;
    s16x8 af[16];
#define HL(K) asm volatile("global_load_dwordx4 %0, %1, off offset:%c2 sc0 sc1" \
                           : "=v"(af[K]) : "v"(hrow), "i"((K)*64))
    HL(0); HL(1); HL(2); HL(3); HL(4); HL(5); HL(6); HL(7);
    HL(8); HL(9); HL(10); HL(11); HL(12); HL(13); HL(14); HL(15);
#undef HL

    f32x4 acc0 = (f32x4){0.f,0.f,0.f,0.f};
    f32x4 acc1 = (f32x4){0.f,0.f,0.f,0.f};
    asm volatile("s_waitcnt vmcnt(8)" ::: "memory");
    __builtin_amdgcn_sched_barrier(0);
#pragma unroll
    for (int ks = 0; ks < 8; ++ks){
      acc0 = MFMA_BF16(af[ks], breg[ks],      acc0);
      acc1 = MFMA_BF16(af[ks], breg[16 + ks], acc1);
    }
    asm volatile("s_waitcnt vmcnt(0)" ::: "memory");
    __builtin_amdgcn_sched_barrier(0);
#pragma unroll
    for (int ks = 8; ks < 16; ++ks){
      acc0 = MFMA_BF16(af[ks], breg[ks],      acc0);
      acc1 = MFMA_BF16(af[ks], breg[16 + ks], acc1);
    }

    // ---- partials -> LDS
#pragma unroll
    for (int r = 0; r < 4; ++r){
      const int bl = rq*4 + r;
      part[(wv*16 + bl)*33 + c16]      = acc0[r];
      part[(wv*16 + bl)*33 + 16 + c16] = acc1[r];
    }
    __syncthreads();

    // ---- epilogue: sum K-halves, activations, state update
    const int mt_e = eb >> 4, bl_e = eb & 15;
    const int b0 = ((mt_e*2 + 0)*16 + bl_e)*33;
    const int b1 = ((mt_e*2 + 1)*16 + bl_e)*33;
    const float vi = part[b0 + ej*4 + 0] + part[b1 + ej*4 + 0] + xp0;
    const float vf = part[b0 + ej*4 + 1] + part[b1 + ej*4 + 1] + xp1;
    const float vg = part[b0 + ej*4 + 2] + part[b1 + ej*4 + 2] + xp2;
    const float vo = part[b0 + ej*4 + 3] + part[b1 + ej*4 + 3] + xp3;

    const float ig = 1.f/(1.f + __expf(-vi));
    const float fg = 1.f/(1.f + __expf(-vf));
    const float gg = tanhf(vg);
    const float og = 1.f/(1.f + __expf(-vo));
    creg = fg*creg + ig*gg;
    const float h = og * tanhf(creg);

    const size_t oidx = (size_t)eb*HID + hc0 + ej;
    outp[(size_t)t*65536 + oidx] = h;                 // normal cached store
    {
      unsigned short hb16 = f2bf(h);
      const unsigned short* hp = hbuf + (size_t)wb*65536 + oidx;
      asm volatile("global_store_short %0, %1, off sc0 sc1"
                   :: "v"(hp), "v"(hb16) : "memory");
    }
    if (t == SEQ-1){
      outp[(size_t)SEQ*65536 + oidx]         = h;     // h_last
      outp[(size_t)SEQ*65536 + 65536 + oidx] = creg;  // c_last
    }

    // ---- release: drain stores (acks = data at LLC), then flag
    asm volatile("s_waitcnt vmcnt(0)" ::: "memory");
    __syncthreads();
    if (tid == 0){
      unsigned int* fp = bar + (blockIdx.x << 5);
      unsigned int fv = (unsigned int)(t + 1);
      asm volatile("global_store_dword %0, %1, off sc0 sc1"
                   :: "v"(fp), "v"(fv) : "memory");
    }
    // ---- acquire: 128 threads poll 128 flags in parallel (LLC loads)
    if (tid < 128){
      const unsigned int* fq = bar + (tid << 5);
      unsigned int fv; int spins = 0;
      do {
        asm volatile("global_load_dword %0, %1, off sc0 sc1\n\ts_waitcnt vmcnt(0)"
                     : "=v"(fv) : "v"(fq) : "memory");
      } while (fv < (unsigned int)(t + 1) && ++spins < (1 << 17));
    }
    __syncthreads();

    rb = wb;
  }

  cstate[(size_t)eb*HID + hc0 + ej] = creg;
}

// ---------------------------------------------------------------------------
extern "C" void kernel_launch(void* const* d_in, const int* in_sizes, int n_in,
                              void* d_out, int out_size, void* d_ws, size_t ws_size,
                              hipStream_t stream)
{
  const float* inp = (const float*)d_in[0];
  const float* wih = (const float*)d_in[1];
  const float* whh = (const float*)d_in[2];
  const float* bih = (const float*)d_in[3];
  const float* bhh = (const float*)d_in[4];
  const float* h0  = (const float*)d_in[5];
  const float* c0  = (const float*)d_in[6];
  float* outp = (float*)d_out;

  auto alignup = [](size_t x){ return (x + 255) & ~(size_t)255; };
  auto need = [&](size_t ch)->size_t{
    size_t s = 0;
    s += alignup(ch*64*4096*4);          // xproj chunk
    s += alignup(ch*64*1024*2);          // in_bf16 chunk
    s += alignup((size_t)4096*1024*2);   // wih_bf16
    s += alignup((size_t)4096*1024*2);   // whh_bf16
    s += alignup((size_t)3*64*1024*2);   // hbuf ring
    s += alignup((size_t)64*1024*4);     // cstate
    s += alignup((size_t)128*32*4);      // flags
    return s;
  };
  int CH = 512;
  while (CH > 2 && need(CH) > ws_size) CH >>= 1;

  char* w = (char*)d_ws;
  float*          xproj  = (float*)w;          w += alignup((size_t)CH*64*4096*4);
  unsigned short* in_bf  = (unsigned short*)w; w += alignup((size_t)CH*64*1024*2);
  unsigned short* wih_bf = (unsigned short*)w; w += alignup((size_t)4096*1024*2);
  unsigned short* whh_bf = (unsigned short*)w; w += alignup((size_t)4096*1024*2);
  unsigned short* hbuf   = (unsigned short*)w; w += alignup((size_t)3*64*1024*2);
  float*          cst    = (float*)w;          w += alignup((size_t)64*1024*4);
  unsigned int*   bar    = (unsigned int*)w;

  hipMemsetAsync(bar, 0, 128*32*4, stream);

  cvt_bf16<<<4096, 256, 0, stream>>>(wih, wih_bf, 4096*1024/4);
  cvt_bf16<<<4096, 256, 0, stream>>>(whh, whh_bf, 4096*1024/4);
  init_state<<<256, 256, 0, stream>>>(h0, c0, hbuf, cst);

  const int nch = SEQ / CH;
  for (int ci = 0; ci < nch; ++ci){
    const int t0 = ci * CH;
    const int n4 = CH*64*1024/4;
    cvt_bf16<<<(n4+255)/256, 256, 0, stream>>>(inp + (size_t)t0*65536, in_bf, n4);
    gemm_xproj<<<dim3((CH*64/128)*32), 256, 0, stream>>>(in_bf, wih_bf, bih, bhh,
                                                         xproj, CH*64);
    lstm_rec<<<dim3(128), dim3(512), 0, stream>>>(whh_bf, xproj, hbuf, cst, outp,
                                                  bar, t0, CH);
  }
}